// Round 8
// baseline (235.763 us; speedup 1.0000x reference)
//
#include <hip/hip_runtime.h>
#include <hip/hip_bf16.h>

using short8   = __attribute__((ext_vector_type(8))) short;
using floatx4  = __attribute__((ext_vector_type(4))) float;
using floatx16 = __attribute__((ext_vector_type(16))) float;

#define KDIM 768
#define QSCALE 0.18033688011112042f   // 0.125 * log2(e)
#define N1 (8192 * 768)
#define N2 (2304 * 768)
#define N3 (768 * 768)

__device__ __forceinline__ short f2bf(float f) {
    union { float f; unsigned u; } v; v.f = f;
    unsigned r = v.u + 0x7fffu + ((v.u >> 16) & 1u);
    return (short)(r >> 16);
}

__device__ __forceinline__ unsigned pack2bf(float a, float b) {
    __hip_bfloat162 h = __float22bfloat162_rn(float2{a, b});
    union { __hip_bfloat162 h; unsigned u; } c; c.h = h;
    return c.u;
}

__device__ __forceinline__ float fast_exp2(float x) {
#if __has_builtin(__builtin_amdgcn_exp2f)
    return __builtin_amdgcn_exp2f(x);
#else
    return exp2f(x);
#endif
}

__device__ __forceinline__ void async16(const void* g, void* l) {
    __builtin_amdgcn_global_load_lds((const __attribute__((address_space(1))) void*)g,
                                     (__attribute__((address_space(3))) void*)l, 16, 0, 0);
}

// ---------------- fused fp32 -> bf16 convert for all three inputs ----------------
__global__ void cvt_all(const float* __restrict__ a, const float* __restrict__ b,
                        const float* __restrict__ c, short* __restrict__ oa,
                        short* __restrict__ ob, short* __restrict__ oc) {
    int i = (blockIdx.x * blockDim.x + threadIdx.x) * 4;
    const float* src; short* dst;
    if (i < N1)            { src = a + i;            dst = oa + i; }
    else if (i < N1 + N2)  { src = b + (i - N1);     dst = ob + (i - N1); }
    else if (i < N1+N2+N3) { src = c + (i - N1 - N2); dst = oc + (i - N1 - N2); }
    else return;
    float4 v = *(const float4*)src;
    short4 o;
    o.x = f2bf(v.x); o.y = f2bf(v.y); o.z = f2bf(v.z); o.w = f2bf(v.w);
    *(short4*)dst = o;
}

// ---------------- QKV GEMM: C[8192,2304] = X @ W^T, scatter to Q/K/V [bh][s][64] ----------------
// (round-6 version — known good)
__global__ __launch_bounds__(256) void gemm_qkv(
    const short* __restrict__ X, const short* __restrict__ W,
    const float* __restrict__ bias,
    short* __restrict__ Qb, short* __restrict__ Kb, short* __restrict__ Vb)
{
    __shared__ short As[128 * 32];
    __shared__ short Bs[128 * 32];
    int tid = threadIdx.x;
    int w = tid >> 6, l = tid & 63;
    int lane16 = l & 15, quad = l >> 4;
    int wm = w & 1, wn = w >> 1;
    int m0 = blockIdx.y * 128, n0 = blockIdx.x * 128;

    floatx4 acc[4][4] = {};

    int srow = w * 32 + (l >> 2);
    int scol = (l & 3) * 8;
    const short* Xg = X + (size_t)(m0 + srow) * KDIM + scol;
    const short* Wg = W + (size_t)(n0 + srow) * KDIM + scol;
    short* AsW = As + (w * 32) * 32;
    short* BsW = Bs + (w * 32) * 32;

    for (int kb = 0; kb < KDIM; kb += 32) {
        __syncthreads();
        async16(Xg + kb,              AsW);
        async16(Xg + kb + 16 * KDIM,  AsW + 16 * 32);
        async16(Wg + kb,              BsW);
        async16(Wg + kb + 16 * KDIM,  BsW + 16 * 32);
        __syncthreads();
        short8 a[4], b[4];
#pragma unroll
        for (int mt = 0; mt < 4; mt++) a[mt] = *(const short8*)(As + (wm * 64 + mt * 16 + lane16) * 32 + quad * 8);
#pragma unroll
        for (int nt = 0; nt < 4; nt++) b[nt] = *(const short8*)(Bs + (wn * 64 + nt * 16 + lane16) * 32 + quad * 8);
#pragma unroll
        for (int mt = 0; mt < 4; mt++)
#pragma unroll
            for (int nt = 0; nt < 4; nt++)
                acc[mt][nt] = __builtin_amdgcn_mfma_f32_16x16x32_bf16(a[mt], b[nt], acc[mt][nt], 0, 0, 0);
    }

#pragma unroll
    for (int mt = 0; mt < 4; mt++) {
        int row = m0 + wm * 64 + mt * 16 + quad * 4;
#pragma unroll
        for (int nt = 0; nt < 4; nt++) {
            int col = n0 + wn * 64 + nt * 16 + lane16;
            int qkv = (col >= 1536) ? 2 : ((col >= 768) ? 1 : 0);
            int rem = col - qkv * 768;
            int h = rem >> 6, e = rem & 63;
            short* dst = (qkv == 0) ? Qb : ((qkv == 1) ? Kb : Vb);
            float sc = (qkv == 0) ? (float)QSCALE : 1.0f;
            float bv = bias[col];
#pragma unroll
            for (int r = 0; r < 4; r++) {
                int i  = row + r;
                int b_ = i >> 11, s_ = i & 2047;
                dst[(((size_t)(b_ * 12 + h)) * 2048 + s_) * 64 + e] = f2bf((acc[mt][nt][r] + bv) * sc);
            }
        }
    }
}

// ---------------- V transpose + sigma key-permute: Vb [bh][s][64] -> Vt [bh][e][64-key tiles] ----------------
__global__ __launch_bounds__(256) void transpose_v(
    const short* __restrict__ Vb, short* __restrict__ Vt)
{
    __shared__ short T[64 * 66];
    int tid = threadIdx.x;
    int s0 = blockIdx.x * 64, bh = blockIdx.y;
    const short* src = Vb + (size_t)bh * 2048 * 64;
    short* dst = Vt + (size_t)bh * 64 * 2048;

#pragma unroll
    for (int i = 0; i < 2; i++) {
        int slot = i * 256 + tid;
        int s_loc = slot >> 3, ec = slot & 7;
        short8 v = *(const short8*)(src + (size_t)(s0 + s_loc) * 64 + ec * 8);
        *(short8*)(T + s_loc * 66 + ec * 8) = v;
    }
    __syncthreads();
#pragma unroll
    for (int i = 0; i < 2; i++) {
        int slot = i * 256 + tid;
        int e_loc = slot >> 3, sc = slot & 7;
        short8 o;
#pragma unroll
        for (int j = 0; j < 8; j++) {
            int p = sc * 8 + j;
            int kp = (p & 0x33) | ((p & 4) << 1) | ((p & 8) >> 1);   // sigma: swap bits 2,3
            o[j] = T[kp * 66 + e_loc];
        }
        *(short8*)(dst + (size_t)e_loc * 2048 + s0 + sc * 8) = o;
    }
}

// ---------------- flash attention: transposed QK^T, P in registers, DOUBLE-BUFFERED K/V ----------------
// grid (16,48), 256 thr / 4 waves, 32 q-rows/wave, 12 waves/CU.
// One barrier per kt: prefetch kt+1 into buf^1 right after the barrier, compute kt on buf.
// The vmcnt(0) drain at the next barrier then waits on loads that flew for a full compute phase.
__global__ __launch_bounds__(256, 3) void attn(
    const short* __restrict__ Qb, const short* __restrict__ Kb,
    const short* __restrict__ Vt, short* __restrict__ Ctx)
{
    __shared__ short Ks[2][512 * 8];
    __shared__ short Vs[2][512 * 8];
    int tid = threadIdx.x, w = tid >> 6, l = tid & 63;
    int l32 = l & 31, half = l >> 5;
    int qt = blockIdx.x, bh = blockIdx.y;
    const short* Qh  = Qb + (size_t)bh * 2048 * 64;
    const short* Kh  = Kb + (size_t)bh * 2048 * 64;
    const short* Vth = Vt + (size_t)bh * 64 * 2048;
    int qbase = qt * 128 + w * 32;

    const short* kSrc[2];
    const short* vSrc[2];
    short* kDst[2][2];   // [buf][i]
    short* vDst[2][2];
#pragma unroll
    for (int i = 0; i < 2; i++) {
        int slot = i * 256 + tid;
        int row = slot >> 3;
        int g = (slot & 7) ^ (row & 7);
        kSrc[i] = Kh + (size_t)row * 64 + g * 8;
        vSrc[i] = Vth + (size_t)row * 2048 + g * 8;
#pragma unroll
        for (int b = 0; b < 2; b++) {
            kDst[b][i] = &Ks[b][(size_t)(i * 256 + w * 64) * 8];  // wave-uniform base
            vDst[b][i] = &Vs[b][(size_t)(i * 256 + w * 64) * 8];
        }
    }

    short8 qf[4];
#pragma unroll
    for (int ks = 0; ks < 4; ks++)
        qf[ks] = *(const short8*)(Qh + (size_t)(qbase + l32) * 64 + ks * 16 + half * 8);

    float lsum = 0.f;
    floatx16 acc[2] = {};
    int sw = l32 & 7;

    // prologue: loads for kt=0 into buf 0
#pragma unroll
    for (int i = 0; i < 2; i++) {
        async16(kSrc[i], kDst[0][i]);
        async16(vSrc[i], vDst[0][i]);
    }

    for (int kt = 0; kt < 32; kt++) {
        __syncthreads();   // waits on buf[kt&1] loads (in flight for a full compute phase)
        int b = kt & 1;
        if (kt < 31) {
            int nb = b ^ 1;
#pragma unroll
            for (int i = 0; i < 2; i++) {
                async16(kSrc[i] + (size_t)(kt + 1) * 64 * 64, kDst[nb][i]);
                async16(vSrc[i] + (size_t)(kt + 1) * 64,      vDst[nb][i]);
            }
        }
        const short* KsB = Ks[b];
        const short* VsB = Vs[b];

        // S^T: A = K-frag (m = key), B = Q-frag (n = q) -> col = q = l32
        floatx16 s[2];
#pragma unroll
        for (int nt = 0; nt < 2; nt++) {
            floatx16 c = {};
            int rowb = (nt * 32 + l32) * 8;
#pragma unroll
            for (int ks = 0; ks < 4; ks++) {
                short8 kf = *(const short8*)(KsB + (size_t)(rowb + ((ks * 2 + half) ^ sw)) * 8);
                c = __builtin_amdgcn_mfma_f32_32x32x16_bf16(kf, qf[ks], c, 0, 0, 0);
            }
            s[nt] = c;
        }

        // exp2 + row-sum + pack P into A-fragments (registers)
        union { short8 s8; unsigned u[4]; } pa[4];
#pragma unroll
        for (int nt = 0; nt < 2; nt++)
#pragma unroll
            for (int r = 0; r < 16; r += 2) {
                float p0 = fast_exp2(s[nt][r]);
                float p1 = fast_exp2(s[nt][r + 1]);
                lsum += p0 + p1;
                pa[2 * nt + (r >> 3)].u[(r & 7) >> 1] = pack2bf(p0, p1);
            }

        // PV: A = P (registers), B = V^T tile (sigma key order)
#pragma unroll
        for (int nt = 0; nt < 2; nt++) {
            int rowb = (nt * 32 + l32) * 8;
#pragma unroll
            for (int ks = 0; ks < 4; ks++) {
                short8 vf = *(const short8*)(VsB + (size_t)(rowb + ((ks * 2 + half) ^ sw)) * 8);
                acc[nt] = __builtin_amdgcn_mfma_f32_32x32x16_bf16(pa[ks].s8, vf, acc[nt], 0, 0, 0);
            }
        }
    }

    float denom = lsum + __shfl_xor(lsum, 32);
    float inv_self = 1.0f / denom;

    int b_ = bh / 12, h = bh % 12;
#pragma unroll
    for (int nt = 0; nt < 2; nt++)
#pragma unroll
        for (int r = 0; r < 16; r++) {
            int qloc = (r & 3) + 8 * (r >> 2) + 4 * half;
            float invq = __shfl(inv_self, qloc);
            int q = qbase + qloc;
            int e = nt * 32 + l32;
            Ctx[((size_t)(b_ * 2048 + q)) * 768 + h * 64 + e] = f2bf(acc[nt][r] * invq);
        }
}

// ---------------- proj GEMM: out[8192,768] = Ctx @ W2^T + b, fp32 out ----------------
// 64x128 tiles -> grid (6,128) = 768 blocks = even 3 blocks/CU.
__global__ __launch_bounds__(256) void gemm_out(
    const short* __restrict__ Ctx, const short* __restrict__ W,
    const float* __restrict__ bias, float* __restrict__ out)
{
    __shared__ short As[64 * 32];
    __shared__ short Bs[128 * 32];
    int tid = threadIdx.x;
    int w = tid >> 6, l = tid & 63;
    int lane16 = l & 15, quad = l >> 4;
    int m0 = blockIdx.y * 64, n0 = blockIdx.x * 128;

    floatx4 acc[4][2] = {};

    const short* XgA = Ctx + (size_t)(m0 + (tid >> 2)) * KDIM + (tid & 3) * 8;
    short* AsD = As + (size_t)(w * 64) * 8;
    const short* XgB[2];
    short* BsD[2];
#pragma unroll
    for (int i = 0; i < 2; i++) {
        int unit = i * 256 + tid;
        XgB[i] = W + (size_t)(n0 + (unit >> 2)) * KDIM + (unit & 3) * 8;
        BsD[i] = Bs + (size_t)(i * 256 + w * 64) * 8;
    }

    for (int kb = 0; kb < KDIM; kb += 32) {
        __syncthreads();
        async16(XgA + kb, AsD);
        async16(XgB[0] + kb, BsD[0]);
        async16(XgB[1] + kb, BsD[1]);
        __syncthreads();
        short8 a[4], b[2];
#pragma unroll
        for (int mt = 0; mt < 4; mt++) a[mt] = *(const short8*)(As + (mt * 16 + lane16) * 32 + quad * 8);
#pragma unroll
        for (int nt = 0; nt < 2; nt++) b[nt] = *(const short8*)(Bs + (w * 32 + nt * 16 + lane16) * 32 + quad * 8);
#pragma unroll
        for (int mt = 0; mt < 4; mt++)
#pragma unroll
            for (int nt = 0; nt < 2; nt++)
                acc[mt][nt] = __builtin_amdgcn_mfma_f32_16x16x32_bf16(a[mt], b[nt], acc[mt][nt], 0, 0, 0);
    }

#pragma unroll
    for (int mt = 0; mt < 4; mt++) {
        int row = m0 + mt * 16 + quad * 4;
#pragma unroll
        for (int nt = 0; nt < 2; nt++) {
            int col = n0 + w * 32 + nt * 16 + lane16;
            float bv = bias[col];
#pragma unroll
            for (int r = 0; r < 4; r++)
                out[(size_t)(row + r) * 768 + col] = acc[mt][nt][r] + bv;
        }
    }
}

extern "C" void kernel_launch(void* const* d_in, const int* in_sizes, int n_in,
                              void* d_out, int out_size, void* d_ws, size_t ws_size,
                              hipStream_t stream) {
    const float* hs     = (const float*)d_in[0];
    const float* qkv_w  = (const float*)d_in[1];
    const float* qkv_b  = (const float*)d_in[2];
    const float* proj_w = (const float*)d_in[3];
    const float* proj_b = (const float*)d_in[4];
    float* out = (float*)d_out;

    short* Xb  = (short*)d_ws;                     // 8192*768 (dead after gemm_qkv; reused as Vt)
    short* W1b = Xb  + (size_t)8192 * 768;         // 2304*768
    short* W2b = W1b + (size_t)2304 * 768;         // 768*768
    short* Qb  = W2b + (size_t)768 * 768;          // 48*2048*64
    short* Kb  = Qb  + (size_t)8192 * 768;
    short* Vb  = Kb  + (size_t)8192 * 768;
    short* Ctx = Vb  + (size_t)8192 * 768;         // 8192*768
    short* Vt  = Xb;                               // [bh][64][2048] sigma-ordered, overlays dead Xb

    int ntot = (N1 + N2 + N3) / 4;
    cvt_all<<<(ntot + 255) / 256, 256, 0, stream>>>(hs, qkv_w, proj_w, Xb, W1b, W2b);

    gemm_qkv<<<dim3(18, 64), 256, 0, stream>>>(Xb, W1b, qkv_b, Qb, Kb, Vb);
    transpose_v<<<dim3(32, 48), 256, 0, stream>>>(Vb, Vt);
    attn<<<dim3(16, 48), 256, 0, stream>>>(Qb, Kb, Vt, Ctx);
    gemm_out<<<dim3(6, 128), 256, 0, stream>>>(Ctx, W2b, proj_b, out);
}

// Round 9
// 229.771 us; speedup vs baseline: 1.0261x; 1.0261x over previous
//
#include <hip/hip_runtime.h>
#include <hip/hip_bf16.h>

using short8   = __attribute__((ext_vector_type(8))) short;
using floatx4  = __attribute__((ext_vector_type(4))) float;
using floatx16 = __attribute__((ext_vector_type(16))) float;

#define KDIM 768
#define QSCALE 0.18033688011112042f   // 0.125 * log2(e)
#define N1 (8192 * 768)
#define N2 (2304 * 768)
#define N3 (768 * 768)

__device__ __forceinline__ short f2bf(float f) {
    union { float f; unsigned u; } v; v.f = f;
    unsigned r = v.u + 0x7fffu + ((v.u >> 16) & 1u);
    return (short)(r >> 16);
}

__device__ __forceinline__ unsigned pack2bf(float a, float b) {
    __hip_bfloat162 h = __float22bfloat162_rn(float2{a, b});
    union { __hip_bfloat162 h; unsigned u; } c; c.h = h;
    return c.u;
}

__device__ __forceinline__ float fast_exp2(float x) {
#if __has_builtin(__builtin_amdgcn_exp2f)
    return __builtin_amdgcn_exp2f(x);
#else
    return exp2f(x);
#endif
}

__device__ __forceinline__ void async16(const void* g, void* l) {
    __builtin_amdgcn_global_load_lds((const __attribute__((address_space(1))) void*)g,
                                     (__attribute__((address_space(3))) void*)l, 16, 0, 0);
}

// ---------------- fused fp32 -> bf16 convert for all three inputs ----------------
__global__ void cvt_all(const float* __restrict__ a, const float* __restrict__ b,
                        const float* __restrict__ c, short* __restrict__ oa,
                        short* __restrict__ ob, short* __restrict__ oc) {
    int i = (blockIdx.x * blockDim.x + threadIdx.x) * 4;
    const float* src; short* dst;
    if (i < N1)            { src = a + i;            dst = oa + i; }
    else if (i < N1 + N2)  { src = b + (i - N1);     dst = ob + (i - N1); }
    else if (i < N1+N2+N3) { src = c + (i - N1 - N2); dst = oc + (i - N1 - N2); }
    else return;
    float4 v = *(const float4*)src;
    short4 o;
    o.x = f2bf(v.x); o.y = f2bf(v.y); o.z = f2bf(v.z); o.w = f2bf(v.w);
    *(short4*)dst = o;
}

// ---------------- QKV GEMM: C[8192,2304] = X @ W^T, scatter to Q/K/V [bh][s][64] ----------------
__global__ __launch_bounds__(256) void gemm_qkv(
    const short* __restrict__ X, const short* __restrict__ W,
    const float* __restrict__ bias,
    short* __restrict__ Qb, short* __restrict__ Kb, short* __restrict__ Vb)
{
    __shared__ short As[128 * 32];
    __shared__ short Bs[128 * 32];
    int tid = threadIdx.x;
    int w = tid >> 6, l = tid & 63;
    int lane16 = l & 15, quad = l >> 4;
    int wm = w & 1, wn = w >> 1;
    int m0 = blockIdx.y * 128, n0 = blockIdx.x * 128;

    floatx4 acc[4][4] = {};

    int srow = w * 32 + (l >> 2);
    int scol = (l & 3) * 8;
    const short* Xg = X + (size_t)(m0 + srow) * KDIM + scol;
    const short* Wg = W + (size_t)(n0 + srow) * KDIM + scol;
    short* AsW = As + (w * 32) * 32;
    short* BsW = Bs + (w * 32) * 32;

    for (int kb = 0; kb < KDIM; kb += 32) {
        __syncthreads();
        async16(Xg + kb,              AsW);
        async16(Xg + kb + 16 * KDIM,  AsW + 16 * 32);
        async16(Wg + kb,              BsW);
        async16(Wg + kb + 16 * KDIM,  BsW + 16 * 32);
        __syncthreads();
        short8 a[4], b[4];
#pragma unroll
        for (int mt = 0; mt < 4; mt++) a[mt] = *(const short8*)(As + (wm * 64 + mt * 16 + lane16) * 32 + quad * 8);
#pragma unroll
        for (int nt = 0; nt < 4; nt++) b[nt] = *(const short8*)(Bs + (wn * 64 + nt * 16 + lane16) * 32 + quad * 8);
#pragma unroll
        for (int mt = 0; mt < 4; mt++)
#pragma unroll
            for (int nt = 0; nt < 4; nt++)
                acc[mt][nt] = __builtin_amdgcn_mfma_f32_16x16x32_bf16(a[mt], b[nt], acc[mt][nt], 0, 0, 0);
    }

#pragma unroll
    for (int mt = 0; mt < 4; mt++) {
        int row = m0 + wm * 64 + mt * 16 + quad * 4;
#pragma unroll
        for (int nt = 0; nt < 4; nt++) {
            int col = n0 + wn * 64 + nt * 16 + lane16;
            int qkv = (col >= 1536) ? 2 : ((col >= 768) ? 1 : 0);
            int rem = col - qkv * 768;
            int h = rem >> 6, e = rem & 63;
            short* dst = (qkv == 0) ? Qb : ((qkv == 1) ? Kb : Vb);
            float sc = (qkv == 0) ? (float)QSCALE : 1.0f;
            float bv = bias[col];
#pragma unroll
            for (int r = 0; r < 4; r++) {
                int i  = row + r;
                int b_ = i >> 11, s_ = i & 2047;
                dst[(((size_t)(b_ * 12 + h)) * 2048 + s_) * 64 + e] = f2bf((acc[mt][nt][r] + bv) * sc);
            }
        }
    }
}

// ---------------- V transpose + sigma key-permute: Vb [bh][s][64] -> Vt [bh][e][64-key tiles] ----------------
__global__ __launch_bounds__(256) void transpose_v(
    const short* __restrict__ Vb, short* __restrict__ Vt)
{
    __shared__ short T[64 * 66];
    int tid = threadIdx.x;
    int s0 = blockIdx.x * 64, bh = blockIdx.y;
    const short* src = Vb + (size_t)bh * 2048 * 64;
    short* dst = Vt + (size_t)bh * 64 * 2048;

#pragma unroll
    for (int i = 0; i < 2; i++) {
        int slot = i * 256 + tid;
        int s_loc = slot >> 3, ec = slot & 7;
        short8 v = *(const short8*)(src + (size_t)(s0 + s_loc) * 64 + ec * 8);
        *(short8*)(T + s_loc * 66 + ec * 8) = v;
    }
    __syncthreads();
#pragma unroll
    for (int i = 0; i < 2; i++) {
        int slot = i * 256 + tid;
        int e_loc = slot >> 3, sc = slot & 7;
        short8 o;
#pragma unroll
        for (int j = 0; j < 8; j++) {
            int p = sc * 8 + j;
            int kp = (p & 0x33) | ((p & 4) << 1) | ((p & 8) >> 1);   // sigma: swap bits 2,3
            o[j] = T[kp * 66 + e_loc];
        }
        *(short8*)(dst + (size_t)e_loc * 2048 + s0 + sc * 8) = o;
    }
}

// ---------------- flash attention: 2-wave blocks for barrier decoupling ----------------
// grid (32,48), 128 thr / 2 waves, 32 q-rows/wave, Q-tile 64 -> 1536 blocks = 6/CU,
// 12 waves/CU (occupancy preserved vs round 6; barrier stall now 1/6 of waves not 1/3).
// Single-buffered (dbuf proven harmful: vmcnt(0) drains the prefetch too).
__global__ __launch_bounds__(128, 3) void attn(
    const short* __restrict__ Qb, const short* __restrict__ Kb,
    const short* __restrict__ Vt, short* __restrict__ Ctx)
{
    __shared__ short Ks[512 * 8];      // K tile: [key 64][e 64], swizzled 16B slots
    __shared__ short Vs[512 * 8];      // V^T tile: [e 64][64 sigma-ordered keys]
    int tid = threadIdx.x, w = tid >> 6, l = tid & 63;
    int l32 = l & 31, half = l >> 5;
    int qt = blockIdx.x, bh = blockIdx.y;
    const short* Qh  = Qb + (size_t)bh * 2048 * 64;
    const short* Kh  = Kb + (size_t)bh * 2048 * 64;
    const short* Vth = Vt + (size_t)bh * 64 * 2048;
    int qbase = qt * 64 + w * 32;

    // staging: 512 slots each over 128 threads, 4 async16 per thread per tile
    const short* kSrc[4];
    const short* vSrc[4];
    short* kDst[4];
    short* vDst[4];
#pragma unroll
    for (int i = 0; i < 4; i++) {
        int slot = i * 128 + tid;
        int row = slot >> 3;
        int g = (slot & 7) ^ (row & 7);
        kSrc[i] = Kh + (size_t)row * 64 + g * 8;        // + kt*64*64
        vSrc[i] = Vth + (size_t)row * 2048 + g * 8;     // + kt*64
        kDst[i] = Ks + (size_t)(i * 128 + w * 64) * 8;  // wave-uniform base
        vDst[i] = Vs + (size_t)(i * 128 + w * 64) * 8;
    }

    // Q fragments (B operand): lane holds q = qbase + l32, k = e
    short8 qf[4];
#pragma unroll
    for (int ks = 0; ks < 4; ks++)
        qf[ks] = *(const short8*)(Qh + (size_t)(qbase + l32) * 64 + ks * 16 + half * 8);

    float lsum = 0.f;
    floatx16 acc[2] = {};
    int sw = l32 & 7;

    for (int kt = 0; kt < 32; kt++) {
        __syncthreads();
#pragma unroll
        for (int i = 0; i < 4; i++) {
            async16(kSrc[i] + (size_t)kt * 64 * 64, kDst[i]);
            async16(vSrc[i] + (size_t)kt * 64,      vDst[i]);
        }
        __syncthreads();

        // S^T: A = K-frag (m = key), B = Q-frag (n = q) -> col = q = l32
        floatx16 s[2];
#pragma unroll
        for (int nt = 0; nt < 2; nt++) {
            floatx16 c = {};
            int rowb = (nt * 32 + l32) * 8;
#pragma unroll
            for (int ks = 0; ks < 4; ks++) {
                short8 kf = *(const short8*)(Ks + (size_t)(rowb + ((ks * 2 + half) ^ sw)) * 8);
                c = __builtin_amdgcn_mfma_f32_32x32x16_bf16(kf, qf[ks], c, 0, 0, 0);
            }
            s[nt] = c;
        }

        // exp2 + row-sum + pack P into A-fragments (registers)
        union { short8 s8; unsigned u[4]; } pa[4];
#pragma unroll
        for (int nt = 0; nt < 2; nt++)
#pragma unroll
            for (int r = 0; r < 16; r += 2) {
                float p0 = fast_exp2(s[nt][r]);
                float p1 = fast_exp2(s[nt][r + 1]);
                lsum += p0 + p1;
                pa[2 * nt + (r >> 3)].u[(r & 7) >> 1] = pack2bf(p0, p1);
            }

        // PV: A = P (registers), B = V^T tile (sigma key order)
#pragma unroll
        for (int nt = 0; nt < 2; nt++) {
            int rowb = (nt * 32 + l32) * 8;
#pragma unroll
            for (int ks = 0; ks < 4; ks++) {
                short8 vf = *(const short8*)(Vs + (size_t)(rowb + ((ks * 2 + half) ^ sw)) * 8);
                acc[nt] = __builtin_amdgcn_mfma_f32_32x32x16_bf16(pa[ks].s8, vf, acc[nt], 0, 0, 0);
            }
        }
    }

    float denom = lsum + __shfl_xor(lsum, 32);
    float inv_self = 1.0f / denom;

    int b_ = bh / 12, h = bh % 12;
#pragma unroll
    for (int nt = 0; nt < 2; nt++)
#pragma unroll
        for (int r = 0; r < 16; r++) {
            int qloc = (r & 3) + 8 * (r >> 2) + 4 * half;
            float invq = __shfl(inv_self, qloc);
            int q = qbase + qloc;
            int e = nt * 32 + l32;
            Ctx[((size_t)(b_ * 2048 + q)) * 768 + h * 64 + e] = f2bf(acc[nt][r] * invq);
        }
}

// ---------------- proj GEMM: out[8192,768] = Ctx @ W2^T + b, fp32 out ----------------
// (round-6 128x128 version — 64x128 retile proven worse: barrier amortization wins)
__global__ __launch_bounds__(256) void gemm_out(
    const short* __restrict__ Ctx, const short* __restrict__ W,
    const float* __restrict__ bias, float* __restrict__ out)
{
    __shared__ short As[128 * 32];
    __shared__ short Bs[128 * 32];
    int tid = threadIdx.x;
    int w = tid >> 6, l = tid & 63;
    int lane16 = l & 15, quad = l >> 4;
    int wm = w & 1, wn = w >> 1;
    int m0 = blockIdx.y * 128, n0 = blockIdx.x * 128;

    floatx4 acc[4][4] = {};

    int srow = w * 32 + (l >> 2);
    int scol = (l & 3) * 8;
    const short* Xg = Ctx + (size_t)(m0 + srow) * KDIM + scol;
    const short* Wg = W + (size_t)(n0 + srow) * KDIM + scol;
    short* AsW = As + (w * 32) * 32;
    short* BsW = Bs + (w * 32) * 32;

    for (int kb = 0; kb < KDIM; kb += 32) {
        __syncthreads();
        async16(Xg + kb,             AsW);
        async16(Xg + kb + 16 * KDIM, AsW + 16 * 32);
        async16(Wg + kb,             BsW);
        async16(Wg + kb + 16 * KDIM, BsW + 16 * 32);
        __syncthreads();
        short8 a[4], b[4];
#pragma unroll
        for (int mt = 0; mt < 4; mt++) a[mt] = *(const short8*)(As + (wm * 64 + mt * 16 + lane16) * 32 + quad * 8);
#pragma unroll
        for (int nt = 0; nt < 4; nt++) b[nt] = *(const short8*)(Bs + (wn * 64 + nt * 16 + lane16) * 32 + quad * 8);
#pragma unroll
        for (int mt = 0; mt < 4; mt++)
#pragma unroll
            for (int nt = 0; nt < 4; nt++)
                acc[mt][nt] = __builtin_amdgcn_mfma_f32_16x16x32_bf16(a[mt], b[nt], acc[mt][nt], 0, 0, 0);
    }

#pragma unroll
    for (int mt = 0; mt < 4; mt++) {
        int row = m0 + wm * 64 + mt * 16 + quad * 4;
#pragma unroll
        for (int nt = 0; nt < 4; nt++) {
            int col = n0 + wn * 64 + nt * 16 + lane16;
            float bv = bias[col];
#pragma unroll
            for (int r = 0; r < 4; r++)
                out[(size_t)(row + r) * 768 + col] = acc[mt][nt][r] + bv;
        }
    }
}

extern "C" void kernel_launch(void* const* d_in, const int* in_sizes, int n_in,
                              void* d_out, int out_size, void* d_ws, size_t ws_size,
                              hipStream_t stream) {
    const float* hs     = (const float*)d_in[0];
    const float* qkv_w  = (const float*)d_in[1];
    const float* qkv_b  = (const float*)d_in[2];
    const float* proj_w = (const float*)d_in[3];
    const float* proj_b = (const float*)d_in[4];
    float* out = (float*)d_out;

    short* Xb  = (short*)d_ws;                     // 8192*768 (dead after gemm_qkv; reused as Vt)
    short* W1b = Xb  + (size_t)8192 * 768;         // 2304*768
    short* W2b = W1b + (size_t)2304 * 768;         // 768*768
    short* Qb  = W2b + (size_t)768 * 768;          // 48*2048*64
    short* Kb  = Qb  + (size_t)8192 * 768;
    short* Vb  = Kb  + (size_t)8192 * 768;
    short* Ctx = Vb  + (size_t)8192 * 768;         // 8192*768
    short* Vt  = Xb;                               // [bh][64][2048] sigma-ordered, overlays dead Xb

    int ntot = (N1 + N2 + N3) / 4;
    cvt_all<<<(ntot + 255) / 256, 256, 0, stream>>>(hs, qkv_w, proj_w, Xb, W1b, W2b);

    gemm_qkv<<<dim3(18, 64), 256, 0, stream>>>(Xb, W1b, qkv_b, Qb, Kb, Vb);
    transpose_v<<<dim3(32, 48), 256, 0, stream>>>(Vb, Vt);
    attn<<<dim3(32, 48), 128, 0, stream>>>(Qb, Kb, Vt, Ctx);
    gemm_out<<<dim3(6, 64), 256, 0, stream>>>(Ctx, W2b, proj_b, out);
}

// Round 10
// 225.301 us; speedup vs baseline: 1.0464x; 1.0198x over previous
//
#include <hip/hip_runtime.h>
#include <hip/hip_bf16.h>

using short8   = __attribute__((ext_vector_type(8))) short;
using floatx4  = __attribute__((ext_vector_type(4))) float;
using floatx16 = __attribute__((ext_vector_type(16))) float;

#define KDIM 768
#define QSCALE 0.18033688011112042f   // 0.125 * log2(e)
#define N1 (8192 * 768)
#define N2 (2304 * 768)
#define N3 (768 * 768)

__device__ __forceinline__ short f2bf(float f) {
    union { float f; unsigned u; } v; v.f = f;
    unsigned r = v.u + 0x7fffu + ((v.u >> 16) & 1u);
    return (short)(r >> 16);
}

__device__ __forceinline__ unsigned pack2bf(float a, float b) {
    __hip_bfloat162 h = __float22bfloat162_rn(float2{a, b});
    union { __hip_bfloat162 h; unsigned u; } c; c.h = h;
    return c.u;
}

__device__ __forceinline__ float fast_exp2(float x) {
#if __has_builtin(__builtin_amdgcn_exp2f)
    return __builtin_amdgcn_exp2f(x);
#else
    return exp2f(x);
#endif
}

__device__ __forceinline__ void async16(const void* g, void* l) {
    __builtin_amdgcn_global_load_lds((const __attribute__((address_space(1))) void*)g,
                                     (__attribute__((address_space(3))) void*)l, 16, 0, 0);
}

// ---------------- fused fp32 -> bf16 convert for all three inputs ----------------
__global__ void cvt_all(const float* __restrict__ a, const float* __restrict__ b,
                        const float* __restrict__ c, short* __restrict__ oa,
                        short* __restrict__ ob, short* __restrict__ oc) {
    int i = (blockIdx.x * blockDim.x + threadIdx.x) * 4;
    const float* src; short* dst;
    if (i < N1)            { src = a + i;            dst = oa + i; }
    else if (i < N1 + N2)  { src = b + (i - N1);     dst = ob + (i - N1); }
    else if (i < N1+N2+N3) { src = c + (i - N1 - N2); dst = oc + (i - N1 - N2); }
    else return;
    float4 v = *(const float4*)src;
    short4 o;
    o.x = f2bf(v.x); o.y = f2bf(v.y); o.z = f2bf(v.z); o.w = f2bf(v.w);
    *(short4*)dst = o;
}

// ---------------- QKV GEMM, BK=64 (half the barriers), swizzled LDS ----------------
// C[8192,2304] = X @ W^T, scatter to Q/K/V [bh][s][64].
// LDS tiles 128 rows x 64 shorts as 8 x 16B chunks; slot = row*8 + (chunk ^ (row&7)).
__global__ __launch_bounds__(256) void gemm_qkv(
    const short* __restrict__ X, const short* __restrict__ W,
    const float* __restrict__ bias,
    short* __restrict__ Qb, short* __restrict__ Kb, short* __restrict__ Vb)
{
    __shared__ short As[1024 * 8];
    __shared__ short Bs[1024 * 8];
    int tid = threadIdx.x;
    int w = tid >> 6, l = tid & 63;
    int lane16 = l & 15, quad = l >> 4;
    int wm = w & 1, wn = w >> 1;
    int m0 = blockIdx.y * 128, n0 = blockIdx.x * 128;

    floatx4 acc[4][4] = {};

    const short* aSrc[4];
    const short* bSrc[4];
    short* aDst[4];
    short* bDst[4];
#pragma unroll
    for (int i = 0; i < 4; i++) {
        int slot = i * 256 + tid;
        int row = slot >> 3;
        int g = (slot & 7) ^ (row & 7);
        aSrc[i] = X + (size_t)(m0 + row) * KDIM + g * 8;
        bSrc[i] = W + (size_t)(n0 + row) * KDIM + g * 8;
        aDst[i] = As + (size_t)(i * 256 + w * 64) * 8;   // wave-uniform base
        bDst[i] = Bs + (size_t)(i * 256 + w * 64) * 8;
    }
    int swz = lane16 & 7;

    for (int kb = 0; kb < KDIM; kb += 64) {
        __syncthreads();
#pragma unroll
        for (int i = 0; i < 4; i++) {
            async16(aSrc[i] + kb, aDst[i]);
            async16(bSrc[i] + kb, bDst[i]);
        }
        __syncthreads();
#pragma unroll
        for (int kc = 0; kc < 2; kc++) {
            short8 a[4], b[4];
#pragma unroll
            for (int mt = 0; mt < 4; mt++) {
                int row = wm * 64 + mt * 16 + lane16;
                a[mt] = *(const short8*)(As + (size_t)(row * 8 + ((kc * 4 + quad) ^ swz)) * 8);
            }
#pragma unroll
            for (int nt = 0; nt < 4; nt++) {
                int row = wn * 64 + nt * 16 + lane16;
                b[nt] = *(const short8*)(Bs + (size_t)(row * 8 + ((kc * 4 + quad) ^ swz)) * 8);
            }
#pragma unroll
            for (int mt = 0; mt < 4; mt++)
#pragma unroll
                for (int nt = 0; nt < 4; nt++)
                    acc[mt][nt] = __builtin_amdgcn_mfma_f32_16x16x32_bf16(a[mt], b[nt], acc[mt][nt], 0, 0, 0);
        }
    }

#pragma unroll
    for (int mt = 0; mt < 4; mt++) {
        int row = m0 + wm * 64 + mt * 16 + quad * 4;
#pragma unroll
        for (int nt = 0; nt < 4; nt++) {
            int col = n0 + wn * 64 + nt * 16 + lane16;
            int qkv = (col >= 1536) ? 2 : ((col >= 768) ? 1 : 0);
            int rem = col - qkv * 768;
            int h = rem >> 6, e = rem & 63;
            short* dst = (qkv == 0) ? Qb : ((qkv == 1) ? Kb : Vb);
            float sc = (qkv == 0) ? (float)QSCALE : 1.0f;
            float bv = bias[col];
#pragma unroll
            for (int r = 0; r < 4; r++) {
                int i  = row + r;
                int b_ = i >> 11, s_ = i & 2047;
                dst[(((size_t)(b_ * 12 + h)) * 2048 + s_) * 64 + e] = f2bf((acc[mt][nt][r] + bv) * sc);
            }
        }
    }
}

// ---------------- V transpose + sigma key-permute: Vb [bh][s][64] -> Vt [bh][e][64-key tiles] ----------------
__global__ __launch_bounds__(256) void transpose_v(
    const short* __restrict__ Vb, short* __restrict__ Vt)
{
    __shared__ short T[64 * 66];
    int tid = threadIdx.x;
    int s0 = blockIdx.x * 64, bh = blockIdx.y;
    const short* src = Vb + (size_t)bh * 2048 * 64;
    short* dst = Vt + (size_t)bh * 64 * 2048;

#pragma unroll
    for (int i = 0; i < 2; i++) {
        int slot = i * 256 + tid;
        int s_loc = slot >> 3, ec = slot & 7;
        short8 v = *(const short8*)(src + (size_t)(s0 + s_loc) * 64 + ec * 8);
        *(short8*)(T + s_loc * 66 + ec * 8) = v;
    }
    __syncthreads();
#pragma unroll
    for (int i = 0; i < 2; i++) {
        int slot = i * 256 + tid;
        int e_loc = slot >> 3, sc = slot & 7;
        short8 o;
#pragma unroll
        for (int j = 0; j < 8; j++) {
            int p = sc * 8 + j;
            int kp = (p & 0x33) | ((p & 4) << 1) | ((p & 8) >> 1);   // sigma: swap bits 2,3
            o[j] = T[kp * 66 + e_loc];
        }
        *(short8*)(dst + (size_t)e_loc * 2048 + s0 + sc * 8) = o;
    }
}

// ---------------- flash attention: 128-key staging tiles (half the barriers) ----------------
// grid (16,48), 256 thr / 4 waves, 32 q-rows/wave, 12 waves/CU.
// Per kt: stage K[128 keys][64 e] + V^T[64 e][128 keys] (32 KB), then two 64-key
// compute halves (kh) using the round-6 verified transposed-QK^T + register-P machinery.
__global__ __launch_bounds__(256, 3) void attn(
    const short* __restrict__ Qb, const short* __restrict__ Kb,
    const short* __restrict__ Vt, short* __restrict__ Ctx)
{
    __shared__ short Ks[1024 * 8];     // [key 128][8 e-chunks], slot = row*8 + (chunk^(row&7))
    __shared__ short Vs[1024 * 8];     // [e 64][16 key-chunks], slot = row*16 + (kh*8 | (c^(row&7)))
    int tid = threadIdx.x, w = tid >> 6, l = tid & 63;
    int l32 = l & 31, half = l >> 5;
    int qt = blockIdx.x, bh = blockIdx.y;
    const short* Qh  = Qb + (size_t)bh * 2048 * 64;
    const short* Kh  = Kb + (size_t)bh * 2048 * 64;
    const short* Vth = Vt + (size_t)bh * 64 * 2048;
    int qbase = qt * 128 + w * 32;

    const short* kSrc[4];
    const short* vSrc[4];
    short* kDst[4];
    short* vDst[4];
#pragma unroll
    for (int i = 0; i < 4; i++) {
        int slot = i * 256 + tid;
        int krow = slot >> 3;
        int kg = (slot & 7) ^ (krow & 7);
        kSrc[i] = Kh + (size_t)krow * 64 + kg * 8;          // + kt*128*64
        kDst[i] = Ks + (size_t)(i * 256 + w * 64) * 8;
        int vrow = slot >> 4, c16 = slot & 15;
        int vg = (c16 & 8) | ((c16 & 7) ^ (vrow & 7));
        vSrc[i] = Vth + (size_t)vrow * 2048 + vg * 8;       // + kt*128
        vDst[i] = Vs + (size_t)(i * 256 + w * 64) * 8;
    }

    short8 qf[4];
#pragma unroll
    for (int ks = 0; ks < 4; ks++)
        qf[ks] = *(const short8*)(Qh + (size_t)(qbase + l32) * 64 + ks * 16 + half * 8);

    float lsum = 0.f;
    floatx16 acc[2] = {};
    int sw = l32 & 7;

    for (int kt = 0; kt < 16; kt++) {
        __syncthreads();
#pragma unroll
        for (int i = 0; i < 4; i++) {
            async16(kSrc[i] + (size_t)kt * 128 * 64, kDst[i]);
            async16(vSrc[i] + (size_t)kt * 128,      vDst[i]);
        }
        __syncthreads();

#pragma unroll
        for (int kh = 0; kh < 2; kh++) {
            // S^T: A = K-frag (m = key), B = Q-frag (n = q) -> col = q = l32
            floatx16 s[2];
#pragma unroll
            for (int nt = 0; nt < 2; nt++) {
                floatx16 c = {};
                int rowb = (kh * 64 + nt * 32 + l32) * 8;
#pragma unroll
                for (int ks = 0; ks < 4; ks++) {
                    short8 kf = *(const short8*)(Ks + (size_t)(rowb + ((ks * 2 + half) ^ sw)) * 8);
                    c = __builtin_amdgcn_mfma_f32_32x32x16_bf16(kf, qf[ks], c, 0, 0, 0);
                }
                s[nt] = c;
            }

            // exp2 + row-sum + pack P into A-fragments (registers)
            union { short8 s8; unsigned u[4]; } pa[4];
#pragma unroll
            for (int nt = 0; nt < 2; nt++)
#pragma unroll
                for (int r = 0; r < 16; r += 2) {
                    float p0 = fast_exp2(s[nt][r]);
                    float p1 = fast_exp2(s[nt][r + 1]);
                    lsum += p0 + p1;
                    pa[2 * nt + (r >> 3)].u[(r & 7) >> 1] = pack2bf(p0, p1);
                }

            // PV: A = P (registers), B = V^T tile (sigma key order), key-chunks kh*8..
#pragma unroll
            for (int nt = 0; nt < 2; nt++) {
                int row = nt * 32 + l32;
#pragma unroll
                for (int ks = 0; ks < 4; ks++) {
                    short8 vf = *(const short8*)(Vs + (size_t)(row * 16 + kh * 8 + ((ks * 2 + half) ^ sw)) * 8);
                    acc[nt] = __builtin_amdgcn_mfma_f32_32x32x16_bf16(pa[ks].s8, vf, acc[nt], 0, 0, 0);
                }
            }
        }
    }

    float denom = lsum + __shfl_xor(lsum, 32);
    float inv_self = 1.0f / denom;

    int b_ = bh / 12, h = bh % 12;
#pragma unroll
    for (int nt = 0; nt < 2; nt++)
#pragma unroll
        for (int r = 0; r < 16; r++) {
            int qloc = (r & 3) + 8 * (r >> 2) + 4 * half;
            float invq = __shfl(inv_self, qloc);
            int q = qbase + qloc;
            int e = nt * 32 + l32;
            Ctx[((size_t)(b_ * 2048 + q)) * 768 + h * 64 + e] = f2bf(acc[nt][r] * invq);
        }
}

// ---------------- proj GEMM, BK=64: out[8192,768] = Ctx @ W2^T + b, fp32 out ----------------
__global__ __launch_bounds__(256) void gemm_out(
    const short* __restrict__ Ctx, const short* __restrict__ W,
    const float* __restrict__ bias, float* __restrict__ out)
{
    __shared__ short As[1024 * 8];
    __shared__ short Bs[1024 * 8];
    int tid = threadIdx.x;
    int w = tid >> 6, l = tid & 63;
    int lane16 = l & 15, quad = l >> 4;
    int wm = w & 1, wn = w >> 1;
    int m0 = blockIdx.y * 128, n0 = blockIdx.x * 128;

    floatx4 acc[4][4] = {};

    const short* aSrc[4];
    const short* bSrc[4];
    short* aDst[4];
    short* bDst[4];
#pragma unroll
    for (int i = 0; i < 4; i++) {
        int slot = i * 256 + tid;
        int row = slot >> 3;
        int g = (slot & 7) ^ (row & 7);
        aSrc[i] = Ctx + (size_t)(m0 + row) * KDIM + g * 8;
        bSrc[i] = W + (size_t)(n0 + row) * KDIM + g * 8;
        aDst[i] = As + (size_t)(i * 256 + w * 64) * 8;
        bDst[i] = Bs + (size_t)(i * 256 + w * 64) * 8;
    }
    int swz = lane16 & 7;

    for (int kb = 0; kb < KDIM; kb += 64) {
        __syncthreads();
#pragma unroll
        for (int i = 0; i < 4; i++) {
            async16(aSrc[i] + kb, aDst[i]);
            async16(bSrc[i] + kb, bDst[i]);
        }
        __syncthreads();
#pragma unroll
        for (int kc = 0; kc < 2; kc++) {
            short8 a[4], b[4];
#pragma unroll
            for (int mt = 0; mt < 4; mt++) {
                int row = wm * 64 + mt * 16 + lane16;
                a[mt] = *(const short8*)(As + (size_t)(row * 8 + ((kc * 4 + quad) ^ swz)) * 8);
            }
#pragma unroll
            for (int nt = 0; nt < 4; nt++) {
                int row = wn * 64 + nt * 16 + lane16;
                b[nt] = *(const short8*)(Bs + (size_t)(row * 8 + ((kc * 4 + quad) ^ swz)) * 8);
            }
#pragma unroll
            for (int mt = 0; mt < 4; mt++)
#pragma unroll
                for (int nt = 0; nt < 4; nt++)
                    acc[mt][nt] = __builtin_amdgcn_mfma_f32_16x16x32_bf16(a[mt], b[nt], acc[mt][nt], 0, 0, 0);
        }
    }

#pragma unroll
    for (int mt = 0; mt < 4; mt++) {
        int row = m0 + wm * 64 + mt * 16 + quad * 4;
#pragma unroll
        for (int nt = 0; nt < 4; nt++) {
            int col = n0 + wn * 64 + nt * 16 + lane16;
            float bv = bias[col];
#pragma unroll
            for (int r = 0; r < 4; r++)
                out[(size_t)(row + r) * 768 + col] = acc[mt][nt][r] + bv;
        }
    }
}

extern "C" void kernel_launch(void* const* d_in, const int* in_sizes, int n_in,
                              void* d_out, int out_size, void* d_ws, size_t ws_size,
                              hipStream_t stream) {
    const float* hs     = (const float*)d_in[0];
    const float* qkv_w  = (const float*)d_in[1];
    const float* qkv_b  = (const float*)d_in[2];
    const float* proj_w = (const float*)d_in[3];
    const float* proj_b = (const float*)d_in[4];
    float* out = (float*)d_out;

    short* Xb  = (short*)d_ws;                     // 8192*768 (dead after gemm_qkv; reused as Vt)
    short* W1b = Xb  + (size_t)8192 * 768;         // 2304*768
    short* W2b = W1b + (size_t)2304 * 768;         // 768*768
    short* Qb  = W2b + (size_t)768 * 768;          // 48*2048*64
    short* Kb  = Qb  + (size_t)8192 * 768;
    short* Vb  = Kb  + (size_t)8192 * 768;
    short* Ctx = Vb  + (size_t)8192 * 768;         // 8192*768
    short* Vt  = Xb;                               // [bh][64][2048] sigma-ordered, overlays dead Xb

    int ntot = (N1 + N2 + N3) / 4;
    cvt_all<<<(ntot + 255) / 256, 256, 0, stream>>>(hs, qkv_w, proj_w, Xb, W1b, W2b);

    gemm_qkv<<<dim3(18, 64), 256, 0, stream>>>(Xb, W1b, qkv_b, Qb, Kb, Vb);
    transpose_v<<<dim3(32, 48), 256, 0, stream>>>(Vb, Vt);
    attn<<<dim3(16, 48), 256, 0, stream>>>(Qb, Kb, Vt, Ctx);
    gemm_out<<<dim3(6, 64), 256, 0, stream>>>(Ctx, W2b, proj_b, out);
}